// Round 19
// baseline (4389.975 us; speedup 1.0000x reference)
//
#include <hip/hip_runtime.h>
#include <stdint.h>

#pragma clang fp contract(off)

// ---------------------------------------------------------------------------
// ASRNN_general f32-exact SAMPLE-PER-BLOCK v6 (mask-class-sorted neurons).
// R15/R16/R18 plateau 4.2-4.5ms == est. L2 aggregate BW ceiling. This round:
// per-layer neuron permutation sorted by mask class (cyc,shift,duty) so that
// active lanes are contiguous within waves -> untouched 64B L2 lines skipped
// -> ~2x L2 traffic cut. Permutation is correctness-neutral (any bijection):
// gather chains remain ascending ORIGINAL-k via k-order spike bitmasks built
// from an LDS byte scatter + second ballot. Validated bit-exact core
// (R11-R18, absmax 1.46e-3): cephes exp, ascending-k conditional-add chains,
// separate-rounding elementwise.
// ---------------------------------------------------------------------------

static constexpr int    TS      = 784;
static constexpr size_t WS_WT1  = 0;                    // wh1^T [512][512] f32 (postsyn-permuted cols)
static constexpr size_t WS_WT2A = 1u << 20;             // wi2^T
static constexpr size_t WS_WT2B = 2u << 20;             // wh2^T
static constexpr size_t WS_WT3  = 3u << 20;             // wi3^T
static constexpr size_t WS_M1   = 4u << 20;             // u8 [784][512] (permuted h order)
static constexpr size_t WS_M2   = WS_M1 + (size_t)TS * 512;
static constexpr size_t WS_M3   = WS_M2 + (size_t)TS * 512;
static constexpr size_t WS_FRP  = WS_M3 + (size_t)TS * 512;   // f64 [256][3]
static constexpr size_t WS_PRM  = WS_FRP + 256 * 3 * 8;       // int [3][512]

// ---- bit-exact replica of Eigen/cephes float32 exp (validated R11) --------
__device__ __forceinline__ float exp_np(float x) {
  float q = rintf(x * 1.442695040f);
  float r = __fmaf_rn(-q, 0.693359375f, x);
  r = __fmaf_rn(-q, -2.12194440e-4f, r);
  float r2 = r * r;
  float p = 1.9875691500e-4f;
  p = __fmaf_rn(p, r, 1.3981999507e-3f);
  p = __fmaf_rn(p, r, 8.3334519073e-3f);
  p = __fmaf_rn(p, r, 4.1665795894e-2f);
  p = __fmaf_rn(p, r, 1.6666665459e-1f);
  p = __fmaf_rn(p, r, 5.0000001201e-1f);
  p = __fmaf_rn(p, r2, r);
  p = p + 1.0f;
  return ldexpf(p, (int)q);
}

// ---- faithful replica of create_general_mask (validated R11) --------------
__device__ __forceinline__ int mask_val(int l, int h, int t) {
  const double cmin = (l == 0) ? 2.0 : ((l == 1) ? 4.0 : 8.0);
  const double cmax = (l == 0) ? 8.0 : ((l == 1) ? 16.0 : 32.0);
  const double smax = (l == 0) ? 4.0 : ((l == 1) ? 8.0 : 16.0);
  const double cD = (cmax - cmin) / 511.0;
  const double dD = (0.8 - 0.2) / 511.0;
  const double sD = smax / 511.0;
  const double hd = (double)h;
  double cycd = (h == 511) ? cmax : __dadd_rn(cmin, __dmul_rn(hd, cD));
  double dcd  = (h == 511) ? 0.8  : __dadd_rn(0.2,  __dmul_rn(hd, dD));
  double psd  = (h == 511) ? smax : __dmul_rn(hd, sD);
  int cyc = __double2int_rn(cycd);
  int on  = __double2int_rn(__dmul_rn(dcd, (double)cyc));
  int ps  = __double2int_rn(psd);
  int eff = (ps >= cyc) ? 0 : ps;
  int pos = (t % cyc) - eff;
  if (pos < 0) pos += cyc;
  return (pos < on) ? 1 : 0;
}

// perm: sort neurons by mask class (cyc,eff,on); deterministic rank sort.
// Correctness does not depend on the key — any bijection works.
__global__ void perm_kernel(char* __restrict__ ws) {
  const int tid = threadIdx.x;   // 512
  __shared__ int keys[512];
  int* PRM = (int*)(ws + WS_PRM);
  for (int l = 0; l < 3; ++l) {
    const double cmin = (l == 0) ? 2.0 : ((l == 1) ? 4.0 : 8.0);
    const double cmax = (l == 0) ? 8.0 : ((l == 1) ? 16.0 : 32.0);
    const double smax = (l == 0) ? 4.0 : ((l == 1) ? 8.0 : 16.0);
    const double cD = (cmax - cmin) / 511.0;
    const double dD = (0.8 - 0.2) / 511.0;
    const double sD = smax / 511.0;
    const double hd = (double)tid;
    double cycd = (tid == 511) ? cmax : __dadd_rn(cmin, __dmul_rn(hd, cD));
    double dcd  = (tid == 511) ? 0.8  : __dadd_rn(0.2,  __dmul_rn(hd, dD));
    double psd  = (tid == 511) ? smax : __dmul_rn(hd, sD);
    int cyc = __double2int_rn(cycd);
    int on  = __double2int_rn(__dmul_rn(dcd, (double)cyc));
    int ps  = __double2int_rn(psd);
    int eff = (ps >= cyc) ? 0 : ps;
    int key = cyc * 2048 + eff * 64 + on;
    keys[tid] = key;
    __syncthreads();
    int rank = 0;
    for (int h2 = 0; h2 < 512; ++h2) {
      int k2 = keys[h2];
      rank += (k2 < key) || (k2 == key && h2 < tid);
    }
    PRM[l * 512 + rank] = tid;
    __syncthreads();
  }
}

__global__ void setup_masks(char* __restrict__ ws) {
  const int t = blockIdx.x, tid = threadIdx.x;   // 784 x 256
  const int* PRM = (const int*)(ws + WS_PRM);
  uint8_t* m1 = (uint8_t*)(ws + WS_M1);
  uint8_t* m2 = (uint8_t*)(ws + WS_M2);
  uint8_t* m3 = (uint8_t*)(ws + WS_M3);
  for (int i = tid; i < 512; i += 256) {
    m1[t * 512 + i] = (uint8_t)mask_val(0, PRM[i], t);
    m2[t * 512 + i] = (uint8_t)mask_val(1, PRM[512 + i], t);
    m3[t * 512 + i] = (uint8_t)mask_val(2, PRM[1024 + i], t);
  }
}

__global__ void transpose_kernel(const float* __restrict__ wh1,
                                 const float* __restrict__ wi2,
                                 const float* __restrict__ wh2,
                                 const float* __restrict__ wi3,
                                 char* __restrict__ ws) {
  const int k = blockIdx.x;   // 512 (original presyn index)
  const int m = blockIdx.y;   // 4
  const int* PRM = (const int*)(ws + WS_PRM);
  const float* W = (m == 0) ? wh1 : (m == 1) ? wi2 : (m == 2) ? wh2 : wi3;
  const int* pp = (m == 0) ? PRM : (m == 3) ? (PRM + 1024) : (PRM + 512);
  float* T = (float*)(ws + (size_t)m * (1u << 20));
  for (int j = threadIdx.x; j < 512; j += 256)
    T[(size_t)k * 512 + j] = W[(size_t)pp[j] * 512 + k];
}

// f32 state update; identical arithmetic to R11-R18 (validated).
__device__ __forceinline__ uint32_t upd32(float hin, uint32_t mk, uint32_t osp,
                                          float al, float om, float r, float omr,
                                          float& memv, float& bv) {
  float t1 = r * bv;
  float bn = osp ? (t1 + omr) : t1;
  float bt = 1.8f * bn;
  float Bth = 0.01f + bt;
  float m1 = memv * al;
  float m2 = om * hin;
  float m3 = m1 + m2;
  float mn = osp ? (m3 - Bth) : m3;
  if (!mk) mn = memv;
  uint32_t sn = (mk && (mn - Bth) > 0.0f) ? 1u : 0u;
  memv = mn; bv = bn;
  return sn;
}

// Rank-based list expansion over k-order bitmasks: ascending ORIGINAL k.
__device__ __forceinline__ int expand_list(const uint64_t* __restrict__ bm,
                                           uint32_t mysp, int kidx,
                                           ushort* __restrict__ kl) {
  const int wh = kidx >> 6, bpos = kidx & 63;
  int cnt = 0, rank = 0;
#pragma unroll
  for (int w = 0; w < 8; ++w) {
    uint64_t v = bm[w];
    int pc = __builtin_popcountll(v);
    if (w < wh) rank += pc;
    cnt += pc;
  }
  rank += __builtin_popcountll(bm[wh] & ((1ull << bpos) - 1ull));
  if (mysp) kl[rank] = (ushort)kidx;
  return cnt;
}

// Ascending-k chain from `from`, 16-deep load pipeline (bit-exact order).
__device__ __forceinline__ float gather_from(const float* __restrict__ base,
                                             const ushort* kl, int from, int cnt,
                                             float s) {
  int i = from;
  for (; i + 16 <= cnt; i += 16) {
    float w0  = base[(size_t)kl[i + 0]  << 9];
    float w1  = base[(size_t)kl[i + 1]  << 9];
    float w2  = base[(size_t)kl[i + 2]  << 9];
    float w3  = base[(size_t)kl[i + 3]  << 9];
    float w4  = base[(size_t)kl[i + 4]  << 9];
    float w5  = base[(size_t)kl[i + 5]  << 9];
    float w6  = base[(size_t)kl[i + 6]  << 9];
    float w7  = base[(size_t)kl[i + 7]  << 9];
    float w8  = base[(size_t)kl[i + 8]  << 9];
    float w9  = base[(size_t)kl[i + 9]  << 9];
    float w10 = base[(size_t)kl[i + 10] << 9];
    float w11 = base[(size_t)kl[i + 11] << 9];
    float w12 = base[(size_t)kl[i + 12] << 9];
    float w13 = base[(size_t)kl[i + 13] << 9];
    float w14 = base[(size_t)kl[i + 14] << 9];
    float w15 = base[(size_t)kl[i + 15] << 9];
    s = s + w0;  s = s + w1;  s = s + w2;  s = s + w3;
    s = s + w4;  s = s + w5;  s = s + w6;  s = s + w7;
    s = s + w8;  s = s + w9;  s = s + w10; s = s + w11;
    s = s + w12; s = s + w13; s = s + w14; s = s + w15;
  }
  for (; i + 4 <= cnt; i += 4) {
    float w0 = base[(size_t)kl[i + 0] << 9];
    float w1 = base[(size_t)kl[i + 1] << 9];
    float w2 = base[(size_t)kl[i + 2] << 9];
    float w3 = base[(size_t)kl[i + 3] << 9];
    s = s + w0; s = s + w1; s = s + w2; s = s + w3;
  }
  for (; i < cnt; ++i) s = s + base[(size_t)kl[i] << 9];
  return s;
}

// Dual interleaved ascending-k chains (8+8); each chain keeps its own order.
__device__ __forceinline__ void dual_gather(
    const float* __restrict__ bA, const ushort* __restrict__ klA, int cntA,
    const float* __restrict__ bB, const ushort* __restrict__ klB, int cntB,
    float& outA, float& outB) {
  float a = 0.0f, b = 0.0f;
  int iA = 0, iB = 0;
  while (iA + 8 <= cntA && iB + 8 <= cntB) {
    float wa0 = bA[(size_t)klA[iA + 0] << 9];
    float wa1 = bA[(size_t)klA[iA + 1] << 9];
    float wa2 = bA[(size_t)klA[iA + 2] << 9];
    float wa3 = bA[(size_t)klA[iA + 3] << 9];
    float wa4 = bA[(size_t)klA[iA + 4] << 9];
    float wa5 = bA[(size_t)klA[iA + 5] << 9];
    float wa6 = bA[(size_t)klA[iA + 6] << 9];
    float wa7 = bA[(size_t)klA[iA + 7] << 9];
    float wb0 = bB[(size_t)klB[iB + 0] << 9];
    float wb1 = bB[(size_t)klB[iB + 1] << 9];
    float wb2 = bB[(size_t)klB[iB + 2] << 9];
    float wb3 = bB[(size_t)klB[iB + 3] << 9];
    float wb4 = bB[(size_t)klB[iB + 4] << 9];
    float wb5 = bB[(size_t)klB[iB + 5] << 9];
    float wb6 = bB[(size_t)klB[iB + 6] << 9];
    float wb7 = bB[(size_t)klB[iB + 7] << 9];
    a = a + wa0; a = a + wa1; a = a + wa2; a = a + wa3;
    a = a + wa4; a = a + wa5; a = a + wa6; a = a + wa7;
    b = b + wb0; b = b + wb1; b = b + wb2; b = b + wb3;
    b = b + wb4; b = b + wb5; b = b + wb6; b = b + wb7;
    iA += 8; iB += 8;
  }
  a = gather_from(bA, klA, iA, cntA, a);
  b = gather_from(bB, klB, iB, cntB, b);
  outA = a; outB = b;
}

__global__ __launch_bounds__(512, 1) void rnn_block(
    const float* __restrict__ x,
    const float* __restrict__ wi1, const float* __restrict__ bi1,
    const float* __restrict__ bh1,
    const float* __restrict__ bi2, const float* __restrict__ bh2,
    const float* __restrict__ bi3,
    const float* __restrict__ wo, const float* __restrict__ bo,
    const float* __restrict__ ta1, const float* __restrict__ ta2,
    const float* __restrict__ ta3, const float* __restrict__ tm1,
    const float* __restrict__ tm2, const float* __restrict__ tm3,
    char* __restrict__ ws, float* __restrict__ d_out) {
  const int n   = blockIdx.x;    // sample
  const int tid = threadIdx.x;   // thread slot 0..511
  const float* WT1  = (const float*)(ws + WS_WT1);
  const float* WT2A = (const float*)(ws + WS_WT2A);
  const float* WT2B = (const float*)(ws + WS_WT2B);
  const float* WT3  = (const float*)(ws + WS_WT3);
  const uint8_t* M1 = (const uint8_t*)(ws + WS_M1);
  const uint8_t* M2 = (const uint8_t*)(ws + WS_M2);
  const uint8_t* M3 = (const uint8_t*)(ws + WS_M3);
  const int* PRM = (const int*)(ws + WS_PRM);

  __shared__ uint64_t bmk1[8], bmk2[8];
  __shared__ ushort kl1s[512], kl2s[512];
  __shared__ uint8_t sby1[512], sby2[512];
  __shared__ float outpS[512 * 10];
  __shared__ double red[512];

  const int h1 = PRM[tid];          // this thread's neuron (original index)
  const int h2 = PRM[512 + tid];
  const int h3 = PRM[1024 + tid];

  float al1 = exp_np(-1.0f / tm1[h1]), om1 = 1.0f - al1;
  float ro1 = exp_np(-1.0f / ta1[h1]), omr1 = 1.0f - ro1;
  float al2 = exp_np(-1.0f / tm2[h2]), om2 = 1.0f - al2;
  float ro2 = exp_np(-1.0f / ta2[h2]), omr2 = 1.0f - ro2;
  float al3 = exp_np(-1.0f / tm3[h3]), om3 = 1.0f - al3;
  float ro3 = exp_np(-1.0f / ta3[h3]), omr3 = 1.0f - ro3;
  float wi1v = wi1[h1], bi1v = bi1[h1], bh1v = bh1[h1];
  float bi2v = bi2[h2], bh2v = bh2[h2], bi3v = bi3[h3];

  float wov[10], outp[10];
#pragma unroll
  for (int o = 0; o < 10; ++o) { wov[o] = wo[(size_t)o * 512 + h3]; outp[o] = 0.0f; }

  float mem1 = 0.0f, b1 = 0.01f, c1 = 0.0f;
  float mem2 = 0.0f, b2 = 0.01f, c2 = 0.0f;
  float mem3 = 0.0f, b3 = 0.01f, c3 = 0.0f;
  uint32_t sp1 = 0, sp2 = 0, sp3 = 0;
  int cnt1 = 0, cnt2 = 0;
  float acc1 = 0.0f;                     // stashed G1 (over kl1[t-1])
  uint32_t mk1 = M1[tid];                // layer-1 mask for current t (permuted)

  const float* xrow = x + (size_t)n * 784;
  __syncthreads();

  for (int t = 0; t < TS; ++t) {
    const uint32_t mk2 = M2[t * 512 + tid];
    const uint32_t mk3 = M3[t * 512 + tid];
    const float xv = xrow[t];

    // ---- layer 1 update (acc1 stashed from phase Y of t-1) ----
    float p1 = xv * wi1v;
    p1 = p1 + bi1v;
    p1 = p1 + acc1;
    p1 = p1 + bh1v;
    uint32_t sn1 = upd32(p1, mk1, sp1, al1, om1, ro1, omr1, mem1, b1);
    sp1 = sn1; c1 += (float)sn1;
    sby1[h1] = (uint8_t)sn1;             // scatter to ORIGINAL-k position
    __syncthreads();                     // bar A: sby1 visible; kl1s(Y,t-1) reads done
    uint32_t bv1 = sby1[tid];            // spike of original neuron k=tid
    uint64_t balk1 = __ballot(bv1);      // k-order word (wave w == k range)
    if ((tid & 63) == 0) bmk1[tid >> 6] = balk1;
    __syncthreads();                     // bar B: bmk1 visible
    cnt1 = expand_list(bmk1, bv1, tid, kl1s);
    __syncthreads();                     // bar C: kl1s(t) visible

    // ---- phase X: dual gather G2A(kl1[t]) + G2B(kl2[t-1]) ----
    float a1, a2;
    {
      const int cA = mk2 ? cnt1 : 0;
      const int cB = mk2 ? cnt2 : 0;
      dual_gather(WT2A + tid, kl1s, cA, WT2B + tid, kl2s, cB, a1, a2);
    }
    float p2 = a1 + bi2v;
    p2 = p2 + a2;
    p2 = p2 + bh2v;
    uint32_t sn2 = upd32(p2, mk2, sp2, al2, om2, ro2, omr2, mem2, b2);
    sp2 = sn2; c2 += (float)sn2;
    sby2[h2] = (uint8_t)sn2;
    __syncthreads();                     // bar D: sby2 visible; kl2s(X) reads done
    uint32_t bv2 = sby2[tid];
    uint64_t balk2 = __ballot(bv2);
    if ((tid & 63) == 0) bmk2[tid >> 6] = balk2;
    __syncthreads();                     // bar E: bmk2 visible
    cnt2 = expand_list(bmk2, bv2, tid, kl2s);
    __syncthreads();                     // bar F: kl2s(t) visible

    // ---- phase Y: dual gather G3(kl2[t]) + G1next(kl1[t]) ----
    const uint32_t mk1n = (t + 1 < TS) ? M1[(t + 1) * 512 + tid] : 0u;
    float a3, a1n;
    {
      const int cG3 = mk3 ? cnt2 : 0;
      const int cG1 = mk1n ? cnt1 : 0;
      dual_gather(WT3 + tid, kl2s, cG3, WT1 + tid, kl1s, cG1, a3, a1n);
    }
    acc1 = a1n;
    mk1 = mk1n;
    float p3 = a3 + bi3v;
    uint32_t sn3 = upd32(p3, mk3, sp3, al3, om3, ro3, omr3, mem3, b3);
    sp3 = sn3; c3 += (float)sn3;

    // ---- barrier-free per-thread readout (out_sum not fed back) ----
    if (sn3) {
#pragma unroll
      for (int o = 0; o < 10; ++o) outp[o] = outp[o] + wov[o];
    }
  }

  // ---- outputs: rates (scatter to original neuron indices) ----
  d_out[2560 + (size_t)n * 512 + h1]          = c1 / 784.0f;
  d_out[2560 + 131072 + (size_t)n * 512 + h2] = c2 / 784.0f;
  d_out[2560 + 262144 + (size_t)n * 512 + h3] = c3 / 784.0f;

  // ---- out_sum reduction (reorder-tolerant) ----
#pragma unroll
  for (int o = 0; o < 10; ++o) outpS[tid * 10 + o] = outp[o];
  __syncthreads();
  if (tid < 10) {
    double s = 0.0;
    for (int l = 0; l < 512; ++l) s += (double)outpS[l * 10 + tid];
    s += 784.0 * (double)bo[tid];
    d_out[(size_t)n * 10 + tid] = (float)s / 784.0f;
  }

  // ---- per-block f64 partial sums for layer_fr (exact integers) ----
  double* FRP = (double*)(ws + WS_FRP);
  red[tid] = (double)c1;
  __syncthreads();
  for (int wd = 256; wd > 0; wd >>= 1) {
    if (tid < wd) red[tid] += red[tid + wd];
    __syncthreads();
  }
  if (tid == 0) FRP[n * 3 + 0] = red[0];
  __syncthreads();
  red[tid] = (double)c2;
  __syncthreads();
  for (int wd = 256; wd > 0; wd >>= 1) {
    if (tid < wd) red[tid] += red[tid + wd];
    __syncthreads();
  }
  if (tid == 0) FRP[n * 3 + 1] = red[0];
  __syncthreads();
  red[tid] = (double)c3;
  __syncthreads();
  for (int wd = 256; wd > 0; wd >>= 1) {
    if (tid < wd) red[tid] += red[tid + wd];
    __syncthreads();
  }
  if (tid == 0) FRP[n * 3 + 2] = red[0];
}

__global__ void finalize_fr(char* __restrict__ ws, float* __restrict__ d_out) {
  const int l = threadIdx.x;
  if (l >= 3) return;
  const double* FRP = (const double*)(ws + WS_FRP);
  double s = 0.0;
  for (int n = 0; n < 256; ++n) s += FRP[n * 3 + l];
  d_out[395776 + l] = (float)(s / (131072.0 * 784.0));
}

extern "C" void kernel_launch(void* const* d_in, const int* in_sizes, int n_in,
                              void* d_out, int out_size, void* d_ws, size_t ws_size,
                              hipStream_t stream) {
  (void)in_sizes; (void)n_in; (void)out_size; (void)ws_size;
  const float* x   = (const float*)d_in[0];
  const float* wi1 = (const float*)d_in[1];
  const float* bi1 = (const float*)d_in[2];
  const float* wh1 = (const float*)d_in[3];
  const float* bh1 = (const float*)d_in[4];
  const float* wi2 = (const float*)d_in[5];
  const float* bi2 = (const float*)d_in[6];
  const float* wh2 = (const float*)d_in[7];
  const float* bh2 = (const float*)d_in[8];
  const float* wi3 = (const float*)d_in[9];
  const float* bi3 = (const float*)d_in[10];
  const float* wo  = (const float*)d_in[11];
  const float* bo  = (const float*)d_in[12];
  const float* ta1 = (const float*)d_in[13];
  const float* ta2 = (const float*)d_in[14];
  const float* ta3 = (const float*)d_in[15];
  const float* tm1 = (const float*)d_in[16];
  const float* tm2 = (const float*)d_in[17];
  const float* tm3 = (const float*)d_in[18];
  char*  ws  = (char*)d_ws;
  float* out = (float*)d_out;

  hipLaunchKernelGGL(perm_kernel, dim3(1), dim3(512), 0, stream, ws);
  hipLaunchKernelGGL(setup_masks, dim3(TS), dim3(256), 0, stream, ws);
  hipLaunchKernelGGL(transpose_kernel, dim3(512, 4), dim3(256), 0, stream,
                     wh1, wi2, wh2, wi3, ws);
  hipLaunchKernelGGL(rnn_block, dim3(256), dim3(512), 0, stream,
                     x, wi1, bi1, bh1, bi2, bh2, bi3, wo, bo,
                     ta1, ta2, ta3, tm1, tm2, tm3, ws, out);
  hipLaunchKernelGGL(finalize_fr, dim3(1), dim3(64), 0, stream, ws, out);
}

// Round 20
// 4173.906 us; speedup vs baseline: 1.0518x; 1.0518x over previous
//
#include <hip/hip_runtime.h>
#include <stdint.h>

#pragma clang fp contract(off)

// ---------------------------------------------------------------------------
// ASRNN_general f32-exact SAMPLE-PER-BLOCK v3 (= R15, empirical best 4.18ms).
// FINAL lock-in round. Evidence across R15/R16/R18/R19 (four schedules,
// 4.18-4.39ms): per-CU vector-memory return bandwidth is the binding limit
// (~800KB weight rows per block-step / 64B/cy = 5.2us/step ~= 5.33 measured).
// Bit-exact core (validated R11-R19, absmax 1.46e-3): cephes exp replica,
// ascending-k f32 conditional-add chains, separate-rounding elementwise.
// ---------------------------------------------------------------------------

static constexpr int    TS      = 784;
static constexpr size_t WS_WT1  = 0;                    // wh1^T [512][512] f32
static constexpr size_t WS_WT2A = 1u << 20;             // wi2^T
static constexpr size_t WS_WT2B = 2u << 20;             // wh2^T
static constexpr size_t WS_WT3  = 3u << 20;             // wi3^T
static constexpr size_t WS_M1   = 4u << 20;             // u8 [784][512]
static constexpr size_t WS_M2   = WS_M1 + (size_t)TS * 512;
static constexpr size_t WS_M3   = WS_M2 + (size_t)TS * 512;
static constexpr size_t WS_FRP  = WS_M3 + (size_t)TS * 512;  // f64 [256][3]

// ---- bit-exact replica of Eigen/cephes float32 exp (validated R11) --------
__device__ __forceinline__ float exp_np(float x) {
  float q = rintf(x * 1.442695040f);
  float r = __fmaf_rn(-q, 0.693359375f, x);
  r = __fmaf_rn(-q, -2.12194440e-4f, r);
  float r2 = r * r;
  float p = 1.9875691500e-4f;
  p = __fmaf_rn(p, r, 1.3981999507e-3f);
  p = __fmaf_rn(p, r, 8.3334519073e-3f);
  p = __fmaf_rn(p, r, 4.1665795894e-2f);
  p = __fmaf_rn(p, r, 1.6666665459e-1f);
  p = __fmaf_rn(p, r, 5.0000001201e-1f);
  p = __fmaf_rn(p, r2, r);
  p = p + 1.0f;
  return ldexpf(p, (int)q);
}

// ---- faithful replica of create_general_mask (validated R11) --------------
__device__ __forceinline__ int mask_val(int l, int h, int t) {
  const double cmin = (l == 0) ? 2.0 : ((l == 1) ? 4.0 : 8.0);
  const double cmax = (l == 0) ? 8.0 : ((l == 1) ? 16.0 : 32.0);
  const double smax = (l == 0) ? 4.0 : ((l == 1) ? 8.0 : 16.0);
  const double cD = (cmax - cmin) / 511.0;
  const double dD = (0.8 - 0.2) / 511.0;
  const double sD = smax / 511.0;
  const double hd = (double)h;
  double cycd = (h == 511) ? cmax : __dadd_rn(cmin, __dmul_rn(hd, cD));
  double dcd  = (h == 511) ? 0.8  : __dadd_rn(0.2,  __dmul_rn(hd, dD));
  double psd  = (h == 511) ? smax : __dmul_rn(hd, sD);
  int cyc = __double2int_rn(cycd);
  int on  = __double2int_rn(__dmul_rn(dcd, (double)cyc));
  int ps  = __double2int_rn(psd);
  int eff = (ps >= cyc) ? 0 : ps;
  int pos = (t % cyc) - eff;
  if (pos < 0) pos += cyc;
  return (pos < on) ? 1 : 0;
}

__global__ void setup_masks(char* __restrict__ ws) {
  const int t = blockIdx.x, tid = threadIdx.x;   // 784 x 256
  uint8_t* m1 = (uint8_t*)(ws + WS_M1);
  uint8_t* m2 = (uint8_t*)(ws + WS_M2);
  uint8_t* m3 = (uint8_t*)(ws + WS_M3);
  for (int h = tid; h < 512; h += 256) {
    m1[t * 512 + h] = (uint8_t)mask_val(0, h, t);
    m2[t * 512 + h] = (uint8_t)mask_val(1, h, t);
    m3[t * 512 + h] = (uint8_t)mask_val(2, h, t);
  }
}

__global__ void transpose_kernel(const float* __restrict__ wh1,
                                 const float* __restrict__ wi2,
                                 const float* __restrict__ wh2,
                                 const float* __restrict__ wi3,
                                 char* __restrict__ ws) {
  const int k = blockIdx.x;   // 512
  const int m = blockIdx.y;   // 4
  const float* W = (m == 0) ? wh1 : (m == 1) ? wi2 : (m == 2) ? wh2 : wi3;
  float* T = (float*)(ws + (size_t)m * (1u << 20));
  for (int j = threadIdx.x; j < 512; j += 256)
    T[(size_t)k * 512 + j] = W[(size_t)j * 512 + k];
}

// f32 state update; identical arithmetic to R11-R19 (validated).
__device__ __forceinline__ uint32_t upd32(float hin, uint32_t mk, uint32_t osp,
                                          float al, float om, float r, float omr,
                                          float& memv, float& bv) {
  float t1 = r * bv;
  float bn = osp ? (t1 + omr) : t1;
  float bt = 1.8f * bn;
  float Bth = 0.01f + bt;
  float m1 = memv * al;
  float m2 = om * hin;
  float m3 = m1 + m2;
  float mn = osp ? (m3 - Bth) : m3;
  if (!mk) mn = memv;
  uint32_t sn = (mk && (mn - Bth) > 0.0f) ? 1u : 0u;
  memv = mn; bv = bn;
  return sn;
}

// Rank-based list expansion: O(1) depth, ascending-k by construction.
__device__ __forceinline__ int expand_list(const uint64_t* __restrict__ bm,
                                           uint32_t mysp, int h,
                                           ushort* __restrict__ kl) {
  const int wh = h >> 6, bpos = h & 63;
  int cnt = 0, rank = 0;
#pragma unroll
  for (int w = 0; w < 8; ++w) {
    uint64_t v = bm[w];
    int pc = __builtin_popcountll(v);
    if (w < wh) rank += pc;
    cnt += pc;
  }
  rank += __builtin_popcountll(bm[wh] & ((1ull << bpos) - 1ull));
  if (mysp) kl[rank] = (ushort)h;
  return cnt;
}

// Ascending-k chain from `from`, 16-deep load pipeline (bit-exact order).
__device__ __forceinline__ float gather_from(const float* __restrict__ base,
                                             const ushort* kl, int from, int cnt,
                                             float s) {
  int i = from;
  for (; i + 16 <= cnt; i += 16) {
    float w0  = base[(size_t)kl[i + 0]  << 9];
    float w1  = base[(size_t)kl[i + 1]  << 9];
    float w2  = base[(size_t)kl[i + 2]  << 9];
    float w3  = base[(size_t)kl[i + 3]  << 9];
    float w4  = base[(size_t)kl[i + 4]  << 9];
    float w5  = base[(size_t)kl[i + 5]  << 9];
    float w6  = base[(size_t)kl[i + 6]  << 9];
    float w7  = base[(size_t)kl[i + 7]  << 9];
    float w8  = base[(size_t)kl[i + 8]  << 9];
    float w9  = base[(size_t)kl[i + 9]  << 9];
    float w10 = base[(size_t)kl[i + 10] << 9];
    float w11 = base[(size_t)kl[i + 11] << 9];
    float w12 = base[(size_t)kl[i + 12] << 9];
    float w13 = base[(size_t)kl[i + 13] << 9];
    float w14 = base[(size_t)kl[i + 14] << 9];
    float w15 = base[(size_t)kl[i + 15] << 9];
    s = s + w0;  s = s + w1;  s = s + w2;  s = s + w3;
    s = s + w4;  s = s + w5;  s = s + w6;  s = s + w7;
    s = s + w8;  s = s + w9;  s = s + w10; s = s + w11;
    s = s + w12; s = s + w13; s = s + w14; s = s + w15;
  }
  for (; i + 4 <= cnt; i += 4) {
    float w0 = base[(size_t)kl[i + 0] << 9];
    float w1 = base[(size_t)kl[i + 1] << 9];
    float w2 = base[(size_t)kl[i + 2] << 9];
    float w3 = base[(size_t)kl[i + 3] << 9];
    s = s + w0; s = s + w1; s = s + w2; s = s + w3;
  }
  for (; i < cnt; ++i) s = s + base[(size_t)kl[i] << 9];
  return s;
}

__global__ __launch_bounds__(512, 1) void rnn_block(
    const float* __restrict__ x,
    const float* __restrict__ wi1, const float* __restrict__ bi1,
    const float* __restrict__ bh1,
    const float* __restrict__ bi2, const float* __restrict__ bh2,
    const float* __restrict__ bi3,
    const float* __restrict__ wo, const float* __restrict__ bo,
    const float* __restrict__ ta1, const float* __restrict__ ta2,
    const float* __restrict__ ta3, const float* __restrict__ tm1,
    const float* __restrict__ tm2, const float* __restrict__ tm3,
    char* __restrict__ ws, float* __restrict__ d_out) {
  const int n = blockIdx.x;    // sample
  const int h = threadIdx.x;   // neuron 0..511
  const float* WT1  = (const float*)(ws + WS_WT1);
  const float* WT2A = (const float*)(ws + WS_WT2A);
  const float* WT2B = (const float*)(ws + WS_WT2B);
  const float* WT3  = (const float*)(ws + WS_WT3);
  const uint8_t* M1 = (const uint8_t*)(ws + WS_M1);
  const uint8_t* M2 = (const uint8_t*)(ws + WS_M2);
  const uint8_t* M3 = (const uint8_t*)(ws + WS_M3);

  __shared__ uint64_t bm1s[8], bm2s[8], bm3s[8];
  __shared__ ushort kl1s[512], kl2s[512];
  __shared__ float woS[10 * 513];
  __shared__ double red[512];

  for (int i = h; i < 5120; i += 512) woS[(i / 512) * 513 + (i % 512)] = wo[i];

  float al1 = exp_np(-1.0f / tm1[h]), om1 = 1.0f - al1;
  float ro1 = exp_np(-1.0f / ta1[h]), omr1 = 1.0f - ro1;
  float al2 = exp_np(-1.0f / tm2[h]), om2 = 1.0f - al2;
  float ro2 = exp_np(-1.0f / ta2[h]), omr2 = 1.0f - ro2;
  float al3 = exp_np(-1.0f / tm3[h]), om3 = 1.0f - al3;
  float ro3 = exp_np(-1.0f / ta3[h]), omr3 = 1.0f - ro3;
  float wi1v = wi1[h], bi1v = bi1[h], bh1v = bh1[h];
  float bi2v = bi2[h], bh2v = bh2[h], bi3v = bi3[h];
  float bo_v = (h < 80 && (h & 7) == 0) ? bo[h >> 3] : 0.0f;

  float mem1 = 0.0f, b1 = 0.01f, c1 = 0.0f;
  float mem2 = 0.0f, b2 = 0.01f, c2 = 0.0f;
  float mem3 = 0.0f, b3 = 0.01f, c3 = 0.0f;
  uint32_t sp1 = 0, sp2 = 0, sp3 = 0;
  int cnt1 = 0, cnt2 = 0;      // uniform per-thread registers
  float outv = 0.0f;

  const float* xrow = x + (size_t)n * 784;
  __syncthreads();

  for (int t = 0; t < TS; ++t) {
    const uint32_t mk1 = M1[t * 512 + h];
    const uint32_t mk2 = M2[t * 512 + h];
    const uint32_t mk3 = M3[t * 512 + h];
    const float xv = xrow[t];

    // ---- layer 1 (uses kl1s/cnt1 from t-1) ----
    float acc1 = 0.0f;
    if (mk1 && cnt1 > 0) acc1 = gather_from(WT1 + h, kl1s, 0, cnt1, 0.0f);
    float p1 = xv * wi1v;
    p1 = p1 + bi1v;
    p1 = p1 + acc1;
    p1 = p1 + bh1v;
    uint32_t sn1 = upd32(p1, mk1, sp1, al1, om1, ro1, omr1, mem1, b1);
    sp1 = sn1; c1 += (float)sn1;
    uint64_t bal1 = __ballot(sn1);
    if ((h & 63) == 0) bm1s[h >> 6] = bal1;
    __syncthreads();                       // bm1 visible; kl1s reads done
    cnt1 = expand_list(bm1s, sn1, h, kl1s);
    __syncthreads();                       // kl1s(t) visible

    // ---- layer 2: dual gather (a1 over kl1s(t), a2 over kl2s(t-1)) ----
    float a1 = 0.0f, a2 = 0.0f;
    if (mk2) {
      const float* bA = WT2A + h;
      const float* bB = WT2B + h;
      int iA = 0, iB = 0;
      while (iA + 8 <= cnt1 && iB + 8 <= cnt2) {
        float wa0 = bA[(size_t)kl1s[iA + 0] << 9];
        float wa1 = bA[(size_t)kl1s[iA + 1] << 9];
        float wa2 = bA[(size_t)kl1s[iA + 2] << 9];
        float wa3 = bA[(size_t)kl1s[iA + 3] << 9];
        float wa4 = bA[(size_t)kl1s[iA + 4] << 9];
        float wa5 = bA[(size_t)kl1s[iA + 5] << 9];
        float wa6 = bA[(size_t)kl1s[iA + 6] << 9];
        float wa7 = bA[(size_t)kl1s[iA + 7] << 9];
        float wb0 = bB[(size_t)kl2s[iB + 0] << 9];
        float wb1 = bB[(size_t)kl2s[iB + 1] << 9];
        float wb2 = bB[(size_t)kl2s[iB + 2] << 9];
        float wb3 = bB[(size_t)kl2s[iB + 3] << 9];
        float wb4 = bB[(size_t)kl2s[iB + 4] << 9];
        float wb5 = bB[(size_t)kl2s[iB + 5] << 9];
        float wb6 = bB[(size_t)kl2s[iB + 6] << 9];
        float wb7 = bB[(size_t)kl2s[iB + 7] << 9];
        a1 = a1 + wa0; a1 = a1 + wa1; a1 = a1 + wa2; a1 = a1 + wa3;
        a1 = a1 + wa4; a1 = a1 + wa5; a1 = a1 + wa6; a1 = a1 + wa7;
        a2 = a2 + wb0; a2 = a2 + wb1; a2 = a2 + wb2; a2 = a2 + wb3;
        a2 = a2 + wb4; a2 = a2 + wb5; a2 = a2 + wb6; a2 = a2 + wb7;
        iA += 8; iB += 8;
      }
      a1 = gather_from(bA, kl1s, iA, cnt1, a1);
      a2 = gather_from(bB, kl2s, iB, cnt2, a2);
    }
    float p2 = a1 + bi2v;
    p2 = p2 + a2;
    p2 = p2 + bh2v;
    uint32_t sn2 = upd32(p2, mk2, sp2, al2, om2, ro2, omr2, mem2, b2);
    sp2 = sn2; c2 += (float)sn2;
    uint64_t bal2 = __ballot(sn2);
    if ((h & 63) == 0) bm2s[h >> 6] = bal2;
    __syncthreads();                       // bm2 visible; kl2s reads done
    cnt2 = expand_list(bm2s, sn2, h, kl2s);
    __syncthreads();                       // kl2s(t) visible

    // ---- layer 3 (uses kl2s(t)) ----
    float a3 = 0.0f;
    if (mk3 && cnt2 > 0) a3 = gather_from(WT3 + h, kl2s, 0, cnt2, 0.0f);
    float p3 = a3 + bi3v;
    uint32_t sn3 = upd32(p3, mk3, sp3, al3, om3, ro3, omr3, mem3, b3);
    sp3 = sn3; c3 += (float)sn3;
    uint64_t bal3 = __ballot(sn3);
    if ((h & 63) == 0) bm3s[h >> 6] = bal3;
    __syncthreads();                       // bm3 visible

    // ---- readout: 80 threads (10 o x 8 words), shuffle-8 reduce ----
    if (h < 80) {
      const int w = h & 7;
      uint64_t v = bm3s[w];
      float s = 0.0f;
      const float* wrow = &woS[(h >> 3) * 513 + w * 64];
      while (v) { int b = __builtin_ctzll(v); v &= v - 1; s = s + wrow[b]; }
      s += __shfl_down(s, 4, 8);
      s += __shfl_down(s, 2, 8);
      s += __shfl_down(s, 1, 8);
      if (w == 0) { float vv = outv + s; outv = vv + bo_v; }
    }
  }

  // ---- outputs ----
  d_out[2560 + (size_t)n * 512 + h]          = c1 / 784.0f;
  d_out[2560 + 131072 + (size_t)n * 512 + h] = c2 / 784.0f;
  d_out[2560 + 262144 + (size_t)n * 512 + h] = c3 / 784.0f;
  if (h < 80 && (h & 7) == 0) d_out[(size_t)n * 10 + (h >> 3)] = outv / 784.0f;

  // per-block f64 partial sums for layer_fr (deterministic)
  double* FRP = (double*)(ws + WS_FRP);
  red[h] = (double)c1;
  __syncthreads();
  for (int wd = 256; wd > 0; wd >>= 1) {
    if (h < wd) red[h] += red[h + wd];
    __syncthreads();
  }
  if (h == 0) FRP[n * 3 + 0] = red[0];
  __syncthreads();
  red[h] = (double)c2;
  __syncthreads();
  for (int wd = 256; wd > 0; wd >>= 1) {
    if (h < wd) red[h] += red[h + wd];
    __syncthreads();
  }
  if (h == 0) FRP[n * 3 + 1] = red[0];
  __syncthreads();
  red[h] = (double)c3;
  __syncthreads();
  for (int wd = 256; wd > 0; wd >>= 1) {
    if (h < wd) red[h] += red[h + wd];
    __syncthreads();
  }
  if (h == 0) FRP[n * 3 + 2] = red[0];
}

__global__ void finalize_fr(char* __restrict__ ws, float* __restrict__ d_out) {
  const int l = threadIdx.x;
  if (l >= 3) return;
  const double* FRP = (const double*)(ws + WS_FRP);
  double s = 0.0;
  for (int n = 0; n < 256; ++n) s += FRP[n * 3 + l];
  d_out[395776 + l] = (float)(s / (131072.0 * 784.0));
}

extern "C" void kernel_launch(void* const* d_in, const int* in_sizes, int n_in,
                              void* d_out, int out_size, void* d_ws, size_t ws_size,
                              hipStream_t stream) {
  (void)in_sizes; (void)n_in; (void)out_size; (void)ws_size;
  const float* x   = (const float*)d_in[0];
  const float* wi1 = (const float*)d_in[1];
  const float* bi1 = (const float*)d_in[2];
  const float* wh1 = (const float*)d_in[3];
  const float* bh1 = (const float*)d_in[4];
  const float* wi2 = (const float*)d_in[5];
  const float* bi2 = (const float*)d_in[6];
  const float* wh2 = (const float*)d_in[7];
  const float* bh2 = (const float*)d_in[8];
  const float* wi3 = (const float*)d_in[9];
  const float* bi3 = (const float*)d_in[10];
  const float* wo  = (const float*)d_in[11];
  const float* bo  = (const float*)d_in[12];
  const float* ta1 = (const float*)d_in[13];
  const float* ta2 = (const float*)d_in[14];
  const float* ta3 = (const float*)d_in[15];
  const float* tm1 = (const float*)d_in[16];
  const float* tm2 = (const float*)d_in[17];
  const float* tm3 = (const float*)d_in[18];
  char*  ws  = (char*)d_ws;
  float* out = (float*)d_out;

  hipLaunchKernelGGL(setup_masks, dim3(TS), dim3(256), 0, stream, ws);
  hipLaunchKernelGGL(transpose_kernel, dim3(512, 4), dim3(256), 0, stream,
                     wh1, wi2, wh2, wi3, ws);
  hipLaunchKernelGGL(rnn_block, dim3(256), dim3(512), 0, stream,
                     x, wi1, bi1, bh1, bi2, bh2, bi3, wo, bo,
                     ta1, ta2, ta3, tm1, tm2, tm3, ws, out);
  hipLaunchKernelGGL(finalize_fr, dim3(1), dim3(64), 0, stream, ws, out);
}